// Round 1
// 700.316 us; speedup vs baseline: 1.0252x; 1.0252x over previous
//
#include <hip/hip_runtime.h>

typedef unsigned short u16;
typedef __attribute__((ext_vector_type(8))) short bf16x8;
typedef __attribute__((ext_vector_type(4))) float f32x4;

#define NTOK 32768
#define CC 512
#define HH 8
#define LL 64
#define NBLK 512
#define MTOK 65536

__device__ __forceinline__ u16 f2bf(float f) {
    unsigned int u = __float_as_uint(f);
    unsigned int r = u + 0x7fffu + ((u >> 16) & 1u);
    return (u16)(r >> 16);
}
__device__ __forceinline__ float bf2f(u16 h) {
    return __uint_as_float(((unsigned int)h) << 16);
}
__device__ __forceinline__ bf16x8 bc8(uint4 v) {
    return __builtin_bit_cast(bf16x8, v);
}
__device__ __forceinline__ void dma16(const u16* g, u16* l) {
    __builtin_amdgcn_global_load_lds((const __attribute__((address_space(1))) void*)g,
                                     (__attribute__((address_space(3))) void*)l, 16, 0, 0);
}

// ---------------- kernel 0: x fp32 -> bf16, fused g_block GEMV ----------------
__global__ __launch_bounds__(256) void convert_gblock_kernel(const float* __restrict__ x,
                                                             u16* __restrict__ xbf,
                                                             const float* __restrict__ w_blk,
                                                             const float* __restrict__ b_blk,
                                                             float* __restrict__ gbl) {
    __shared__ float wbs[4608];
    int tid = threadIdx.x;
    for (int i = tid; i < 4096; i += 256) wbs[i + (i >> 6)] = w_blk[i];
    size_t tok = (size_t)blockIdx.x * 4 + (tid >> 6);
    int lane = tid & 63;
    int c0 = lane * 8;
    const float4* p = (const float4*)(x + tok * CC + c0);
    float4 a = p[0], b = p[1];
    uint4 o;
    o.x = (unsigned)f2bf(a.x) | ((unsigned)f2bf(a.y) << 16);
    o.y = (unsigned)f2bf(a.z) | ((unsigned)f2bf(a.w) << 16);
    o.z = (unsigned)f2bf(b.x) | ((unsigned)f2bf(b.y) << 16);
    o.w = (unsigned)f2bf(b.z) | ((unsigned)f2bf(b.w) << 16);
    *(uint4*)(xbf + tok * CC + c0) = o;
    float xv[8] = {a.x, a.y, a.z, a.w, b.x, b.y, b.z, b.w};
    __syncthreads();
    float acc[8];
#pragma unroll
    for (int h = 0; h < 8; ++h) acc[h] = 0.f;
#pragma unroll
    for (int j = 0; j < 8; ++j) {
        const float* wr = &wbs[(c0 + j) * 8 + lane];
#pragma unroll
        for (int h = 0; h < 8; ++h) acc[h] += xv[j] * wr[h];
    }
#pragma unroll
    for (int h = 0; h < 8; ++h) {
#pragma unroll
        for (int off = 1; off < 64; off <<= 1) acc[h] += __shfl_xor(acc[h], off);
    }
    float v = acc[0];
#pragma unroll
    for (int h = 1; h < 8; ++h) v = (lane == h) ? acc[h] : v;
    if (lane < 8) gbl[tok * 8 + lane] = 1.f / (1.f + __expf(-(v + b_blk[lane])));
}

// ---------------- kernel 1: transpose fp32 [K][Nn] -> bf16 [Nn][K] ----------------
__global__ __launch_bounds__(256) void transpose_bf16_kernel(const float* __restrict__ in,
                                                             u16* __restrict__ out,
                                                             int K, int Nn) {
    __shared__ float tile[32][33];
    int n0 = blockIdx.x * 32, k0 = blockIdx.y * 32;
    int tx = threadIdx.x & 31, ty = threadIdx.x >> 5;
#pragma unroll
    for (int i = 0; i < 4; ++i)
        tile[ty + i * 8][tx] = in[(size_t)(k0 + ty + i * 8) * Nn + n0 + tx];
    __syncthreads();
#pragma unroll
    for (int i = 0; i < 4; ++i)
        out[(size_t)(n0 + ty + i * 8) * K + k0 + tx] = f2bf(tile[tx][ty + i * 8]);
}

// ---------------- kernel 2: sbias2/gate2 in MFMA C-fragment layout ----------------
// grid 2048: block = (nb = bid>>2, q-quarter = bid&3); 16 q-rows per block.
__global__ __launch_bounds__(256) void gate_sbias_kernel(const int* __restrict__ mask,
                                                         const float* __restrict__ edge,
                                                         const float* __restrict__ w1,
                                                         const float* __restrict__ b1,
                                                         const float* __restrict__ w2,
                                                         const float* __restrict__ b2,
                                                         u16* __restrict__ gate2,
                                                         u16* __restrict__ sbias2) {
    __shared__ float w1s[64], b1s[16], w2s[128], b2s[8];
    __shared__ int nds[16];
    int t = threadIdx.x;
    int nb = blockIdx.x >> 2;
    int qt = blockIdx.x & 3;
    if (t < 64) w1s[t] = w1[t];
    if (t < 16) b1s[t] = b1[t];
    if (t < 128) w2s[t] = w2[t];
    if (t < 8) b2s[t] = b2[t];
    if (t >= 128 && t < 144) {
        int q = qt * 16 + (t - 128);
        int s = 0;
        const int* mr = mask + (size_t)(nb * 64 + q) * 64;
#pragma unroll 8
        for (int k = 0; k < 64; ++k) s += mr[k];
        nds[t - 128] = (s < 1) ? 1 : 0;
    }
    __syncthreads();
#pragma unroll 1
    for (int it = 0; it < 4; ++it) {
        int p = it * 256 + t;
        int ql = p >> 6, k = p & 63;
        int q = qt * 16 + ql;
        int pk = (k & 15) * 4 + (k >> 4);
        int mv = mask[(size_t)(nb * 64 + q) * 64 + k];
        float e0, e1, e2, e3;
        if (q == k) {
            mv = max(mv, nds[ql]);
            e0 = e1 = e2 = 0.f;
            e3 = 1.f;
        } else {
            const float* ep = edge + ((size_t)(nb * 64 + q) * 64 + k) * 4;
            e0 = ep[0]; e1 = ep[1]; e2 = ep[2]; e3 = ep[3];
        }
        sbias2[(size_t)(nb * 64 + q) * 64 + pk] = f2bf(mv ? e3 : -1e30f);
        float g[8];
#pragma unroll
        for (int hh = 0; hh < 8; ++hh) g[hh] = b2s[hh];
#pragma unroll
        for (int j = 0; j < 16; ++j) {
            float hpre = e0 * w1s[j] + e1 * w1s[16 + j] + e2 * w1s[32 + j] + e3 * w1s[48 + j] + b1s[j];
            float hg = 0.5f * hpre * (1.f + erff(hpre * 0.70710678f));
#pragma unroll
            for (int hh = 0; hh < 8; ++hh) g[hh] += hg * w2s[j * 8 + hh];
        }
#pragma unroll
        for (int hh = 0; hh < 8; ++hh)
            gate2[(((size_t)nb * 8 + hh) * 64 + q) * 64 + pk] = f2bf(mv ? g[hh] : 0.f);
    }
}

// ---------------- m97-style 128x128 GEMM: qkv = xbf @ wqkvT^T + b ----------------
// XCD-chunked swizzle: the 12 n-tiles sharing an A-panel land on one XCD, adjacent in time.
// Output head-major: qkv[plane = col>>6][token][d = col&63], plane in [0,24).
__global__ __launch_bounds__(256) void qkv_gemm_kernel(const u16* __restrict__ xbf,
                                                       const u16* __restrict__ wqkvT,
                                                       const float* __restrict__ b_qkv,
                                                       u16* __restrict__ qkv) {
    __shared__ __align__(16) u16 As[128 * 64], Bs[128 * 64];
    int tid = threadIdx.x;
    int flat = blockIdx.x;                     // 6144 blocks
    int logical = (flat & 7) * 768 + (flat >> 3);
    int n0 = (logical % 12) * 128;
    int m0 = (logical / 12) * 128;
    int lane = tid & 63, l15 = lane & 15, quad = lane >> 4, wave = tid >> 6;
    int r8 = lane >> 3, jch = lane & 7;
    int js = jch ^ r8;
    int mwl = (wave >> 1) * 64, nwl = (wave & 1) * 64;
    int sw = l15 & 7;

    f32x4 acc[4][4];
#pragma unroll
    for (int i = 0; i < 4; ++i)
#pragma unroll
        for (int j = 0; j < 4; ++j) acc[i][j] = (f32x4){0.f, 0.f, 0.f, 0.f};

    int arow[4], brow[4];
#pragma unroll
    for (int i = 0; i < 4; ++i) arow[i] = (mwl + i * 16 + l15) * 64;
#pragma unroll
    for (int j = 0; j < 4; ++j) brow[j] = (nwl + j * 16 + l15) * 64;

    const u16* gA = xbf + (size_t)(m0 + wave * 32 + r8) * CC + js * 8;
    const u16* gB = wqkvT + (size_t)(n0 + wave * 32 + r8) * CC + js * 8;
    u16* lA = As + wave * 32 * 64;
    u16* lB = Bs + wave * 32 * 64;

    for (int kt = 0; kt < 8; ++kt) {
        int k0 = kt * 64;
#pragma unroll
        for (int t = 0; t < 4; ++t) {
            dma16(gA + (size_t)t * 8 * CC + k0, lA + t * 8 * 64);
            dma16(gB + (size_t)t * 8 * CC + k0, lB + t * 8 * 64);
        }
        __syncthreads();
#pragma unroll
        for (int kk = 0; kk < 2; ++kk) {
            int ch = ((kk * 4 + quad) ^ sw) * 8;
            bf16x8 a[4], bb[4];
#pragma unroll
            for (int i = 0; i < 4; ++i) a[i] = *(const bf16x8*)&As[arow[i] + ch];
#pragma unroll
            for (int j = 0; j < 4; ++j) bb[j] = *(const bf16x8*)&Bs[brow[j] + ch];
#pragma unroll
            for (int i = 0; i < 4; ++i)
#pragma unroll
                for (int j = 0; j < 4; ++j)
                    acc[i][j] = __builtin_amdgcn_mfma_f32_16x16x32_bf16(a[i], bb[j], acc[i][j], 0, 0, 0);
        }
        __syncthreads();
    }
#pragma unroll
    for (int i = 0; i < 4; ++i)
#pragma unroll
        for (int j = 0; j < 4; ++j) {
            int col = n0 + nwl + j * 16 + l15;
            int plane = col >> 6;
            int d = col & 63;
            float bp = b_qkv[col];
#pragma unroll
            for (int r = 0; r < 4; ++r) {
                int row = m0 + mwl + i * 16 + quad * 4 + r;
                qkv[((size_t)plane * MTOK + row) * 64 + d] = f2bf(acc[i][j][r] + bp);
            }
        }
}

// ---------------- out = x_mid @ w_proj + b_proj (fp32 out) ----------------
__global__ __launch_bounds__(256) void outproj_kernel(const u16* __restrict__ xmid,
                                                      const u16* __restrict__ wprojT,
                                                      const float* __restrict__ b_proj,
                                                      float* __restrict__ out) {
    __shared__ __align__(16) u16 As[128 * 64], Bs[128 * 64];
    int tid = threadIdx.x;
    int flat = blockIdx.x;                     // 2048 blocks
    int logical = (flat & 7) * 256 + (flat >> 3);
    int n0 = (logical & 3) * 128;
    int m0 = (logical >> 2) * 128;
    int lane = tid & 63, l15 = lane & 15, quad = lane >> 4, wave = tid >> 6;
    int r8 = lane >> 3, jch = lane & 7;
    int js = jch ^ r8;
    int mwl = (wave >> 1) * 64, nwl = (wave & 1) * 64;
    int sw = l15 & 7;

    f32x4 acc[4][4];
#pragma unroll
    for (int i = 0; i < 4; ++i)
#pragma unroll
        for (int j = 0; j < 4; ++j) acc[i][j] = (f32x4){0.f, 0.f, 0.f, 0.f};

    int arow[4], brow[4];
#pragma unroll
    for (int i = 0; i < 4; ++i) arow[i] = (mwl + i * 16 + l15) * 64;
#pragma unroll
    for (int j = 0; j < 4; ++j) brow[j] = (nwl + j * 16 + l15) * 64;

    const u16* gA = xmid + (size_t)(m0 + wave * 32 + r8) * CC + js * 8;
    const u16* gB = wprojT + (size_t)(n0 + wave * 32 + r8) * CC + js * 8;
    u16* lA = As + wave * 32 * 64;
    u16* lB = Bs + wave * 32 * 64;

    for (int kt = 0; kt < 8; ++kt) {
        int k0 = kt * 64;
#pragma unroll
        for (int t = 0; t < 4; ++t) {
            dma16(gA + (size_t)t * 8 * CC + k0, lA + t * 8 * 64);
            dma16(gB + (size_t)t * 8 * CC + k0, lB + t * 8 * 64);
        }
        __syncthreads();
#pragma unroll
        for (int kk = 0; kk < 2; ++kk) {
            int ch = ((kk * 4 + quad) ^ sw) * 8;
            bf16x8 a[4], bb[4];
#pragma unroll
            for (int i = 0; i < 4; ++i) a[i] = *(const bf16x8*)&As[arow[i] + ch];
#pragma unroll
            for (int j = 0; j < 4; ++j) bb[j] = *(const bf16x8*)&Bs[brow[j] + ch];
#pragma unroll
            for (int i = 0; i < 4; ++i)
#pragma unroll
                for (int j = 0; j < 4; ++j)
                    acc[i][j] = __builtin_amdgcn_mfma_f32_16x16x32_bf16(a[i], bb[j], acc[i][j], 0, 0, 0);
        }
        __syncthreads();
    }
#pragma unroll
    for (int i = 0; i < 4; ++i)
#pragma unroll
        for (int j = 0; j < 4; ++j) {
            int col = n0 + nwl + j * 16 + l15;
            float bp = b_proj[col];
#pragma unroll
            for (int r = 0; r < 4; ++r) {
                int row = m0 + mwl + i * 16 + quad * 4 + r;
                out[(size_t)row * CC + col] = acc[i][j][r] + bp;
            }
        }
}

// ---------------- fused per-(b,nb,h) attention (head-major qkv input) ----------------
__global__ __launch_bounds__(256) void attn_kernel(const u16* __restrict__ qkv,
                                                   const u16* __restrict__ sbias2,
                                                   const u16* __restrict__ gate2,
                                                   const float* __restrict__ gbl,
                                                   u16* __restrict__ xmid) {
    __shared__ u16 VT[64 * 72], Ps[64 * 72];
    __shared__ float gl[64], vbl[64];
    int tid = threadIdx.x;
    int bid = blockIdx.x;
    int h = bid & 7, nb = (bid >> 3) & 511, b = bid >> 12;
    int lane = tid & 63, l15 = lane & 15, quad = lane >> 4, wave = tid >> 6;
    int m0 = wave * 16;
    size_t blockrow = (size_t)(b * NTOK + nb * 64);
    const u16* qq = qkv + ((size_t)h * MTOK + blockrow) * 64;
    const u16* qk = qq + (size_t)8 * MTOK * 64;
    const u16* qv = qq + (size_t)16 * MTOK * 64;

    {
        int key = tid & 63, d0 = (tid >> 6) * 16;
        const uint4* vsrc = (const uint4*)(qv + (size_t)key * 64 + d0);
        uint4 v0 = vsrc[0], v1 = vsrc[1];
        u16 tmp[16];
        *(uint4*)tmp = v0;
        *(uint4*)(tmp + 8) = v1;
#pragma unroll
        for (int j = 0; j < 16; ++j) VT[(d0 + j) * 72 + key] = tmp[j];
    }
    if (tid < 64) gl[tid] = gbl[(blockrow + tid) * 8 + h];
    __syncthreads();

    if (tid < 64) {
        float s = 0.f;
#pragma unroll 8
        for (int k = 0; k < 64; ++k) s += bf2f(VT[tid * 72 + k]);
        vbl[tid] = s * 0.015625f;
    }

    f32x4 sc[4];
#pragma unroll
    for (int t = 0; t < 4; ++t) sc[t] = (f32x4){0.f, 0.f, 0.f, 0.f};
#pragma unroll
    for (int kk = 0; kk < 2; ++kk) {
        bf16x8 a = bc8(*(const uint4*)(qq + (size_t)(m0 + l15) * 64 + kk * 32 + quad * 8));
#pragma unroll
        for (int t = 0; t < 4; ++t) {
            bf16x8 bb = bc8(*(const uint4*)(qk + (size_t)(t * 16 + l15) * 64 + kk * 32 + quad * 8));
            sc[t] = __builtin_amdgcn_mfma_f32_16x16x32_bf16(a, bb, sc[t], 0, 0, 0);
        }
    }
    {
        const u16* sb2 = sbias2 + (size_t)nb * 4096;
        const u16* gp2 = gate2 + ((size_t)nb * 8 + h) * 4096;
#pragma unroll
        for (int r = 0; r < 4; ++r) {
            int q = m0 + quad * 4 + r;
            ushort4 sv = *(const ushort4*)(sb2 + (q * 16 + l15) * 4);
            float bias_t[4] = {bf2f(sv.x), bf2f(sv.y), bf2f(sv.z), bf2f(sv.w)};
            float mx = -3e38f;
#pragma unroll
            for (int t = 0; t < 4; ++t) {
                float v = sc[t][r] * 0.125f + bias_t[t];
                sc[t][r] = v;
                mx = fmaxf(mx, v);
            }
            mx = fmaxf(mx, __shfl_xor(mx, 1));
            mx = fmaxf(mx, __shfl_xor(mx, 2));
            mx = fmaxf(mx, __shfl_xor(mx, 4));
            mx = fmaxf(mx, __shfl_xor(mx, 8));
            float sum = 0.f;
#pragma unroll
            for (int t = 0; t < 4; ++t) {
                float p = __expf(sc[t][r] - mx);
                sc[t][r] = p;
                sum += p;
            }
            sum += __shfl_xor(sum, 1);
            sum += __shfl_xor(sum, 2);
            sum += __shfl_xor(sum, 4);
            sum += __shfl_xor(sum, 8);
            float inv = 1.f / sum;
            ushort4 gv = *(const ushort4*)(gp2 + (q * 16 + l15) * 4);
            float gate_t[4] = {bf2f(gv.x), bf2f(gv.y), bf2f(gv.z), bf2f(gv.w)};
#pragma unroll
            for (int t = 0; t < 4; ++t) {
                float comb = sc[t][r] * inv + gate_t[t];
                Ps[q * 72 + t * 16 + l15] = f2bf(comb);
            }
        }
    }
    __syncthreads();

    f32x4 o[4];
#pragma unroll
    for (int t = 0; t < 4; ++t) o[t] = (f32x4){0.f, 0.f, 0.f, 0.f};
#pragma unroll
    for (int kk = 0; kk < 2; ++kk) {
        bf16x8 a = *(const bf16x8*)&Ps[(m0 + l15) * 72 + kk * 32 + quad * 8];
#pragma unroll
        for (int t = 0; t < 4; ++t) {
            bf16x8 bb = *(const bf16x8*)&VT[(t * 16 + l15) * 72 + kk * 32 + quad * 8];
            o[t] = __builtin_amdgcn_mfma_f32_16x16x32_bf16(a, bb, o[t], 0, 0, 0);
        }
    }
#pragma unroll
    for (int t = 0; t < 4; ++t) {
#pragma unroll
        for (int r = 0; r < 4; ++r) {
            int q = m0 + quad * 4 + r, d = t * 16 + l15;
            float v = o[t][r] + gl[q] * vbl[d];
            xmid[(blockrow + q) * CC + h * 64 + d] = f2bf(v);
        }
    }
}

extern "C" void kernel_launch(void* const* d_in, const int* in_sizes, int n_in,
                              void* d_out, int out_size, void* d_ws, size_t ws_size,
                              hipStream_t stream) {
    const float* x = (const float*)d_in[0];
    const int* attn_mask = (const int*)d_in[1];
    const float* edge = (const float*)d_in[2];
    const float* w_qkv = (const float*)d_in[3];
    const float* b_qkv = (const float*)d_in[4];
    const float* w_proj = (const float*)d_in[5];
    const float* b_proj = (const float*)d_in[6];
    const float* w_eg1 = (const float*)d_in[7];
    const float* b_eg1 = (const float*)d_in[8];
    const float* w_eg2 = (const float*)d_in[9];
    const float* b_eg2 = (const float*)d_in[10];
    const float* w_blk = (const float*)d_in[11];
    const float* b_blk = (const float*)d_in[12];
    float* out = (float*)d_out;

    char* ws = (char*)d_ws;
    u16* xbf = (u16*)ws;                            // 67108864 bytes
    u16* xmid = (u16*)ws;                           // alias (xbf consumed before attn writes)
    u16* qkv = (u16*)(ws + 67108864);               // 201326592 (24 planes x 65536 x 64 bf16)
    u16* gate2 = (u16*)(ws + 268435456);            // 33554432
    u16* sbias2 = (u16*)(ws + 301989888);           // 4194304
    u16* wqkvT = (u16*)(ws + 306184192);            // 1572864
    u16* wprojT = (u16*)(ws + 307757056);           // 524288
    float* gbl = (float*)(ws + 308281344);          // 2097152

    convert_gblock_kernel<<<16384, 256, 0, stream>>>(x, xbf, w_blk, b_blk, gbl);
    transpose_bf16_kernel<<<dim3(48, 16), 256, 0, stream>>>(w_qkv, wqkvT, 512, 1536);
    transpose_bf16_kernel<<<dim3(16, 16), 256, 0, stream>>>(w_proj, wprojT, 512, 512);
    gate_sbias_kernel<<<2048, 256, 0, stream>>>(attn_mask, edge, w_eg1, b_eg1, w_eg2, b_eg2,
                                                gate2, sbias2);
    qkv_gemm_kernel<<<6144, 256, 0, stream>>>(xbf, wqkvT, b_qkv, qkv);
    attn_kernel<<<8192, 256, 0, stream>>>(qkv, sbias2, gate2, gbl, xmid);
    outproj_kernel<<<2048, 256, 0, stream>>>(xmid, wprojT, b_proj, out);
}

// Round 2
// 628.735 us; speedup vs baseline: 1.1419x; 1.1138x over previous
//
#include <hip/hip_runtime.h>

typedef unsigned short u16;
typedef __attribute__((ext_vector_type(8))) short bf16x8;
typedef __attribute__((ext_vector_type(4))) float f32x4;

#define NTOK 32768
#define CC 512
#define HH 8
#define LL 64
#define NBLK 512
#define MTOK 65536

__device__ __forceinline__ u16 f2bf(float f) {
    unsigned int u = __float_as_uint(f);
    unsigned int r = u + 0x7fffu + ((u >> 16) & 1u);
    return (u16)(r >> 16);
}
__device__ __forceinline__ float bf2f(u16 h) {
    return __uint_as_float(((unsigned int)h) << 16);
}
__device__ __forceinline__ bf16x8 bc8(uint4 v) {
    return __builtin_bit_cast(bf16x8, v);
}
__device__ __forceinline__ void dma16(const u16* g, u16* l) {
    __builtin_amdgcn_global_load_lds((const __attribute__((address_space(1))) void*)g,
                                     (__attribute__((address_space(3))) void*)l, 16, 0, 0);
}

// ---------------- kernel 0: x fp32 -> bf16, fused g_block GEMV ----------------
__global__ __launch_bounds__(256) void convert_gblock_kernel(const float* __restrict__ x,
                                                             u16* __restrict__ xbf,
                                                             const float* __restrict__ w_blk,
                                                             const float* __restrict__ b_blk,
                                                             float* __restrict__ gbl) {
    __shared__ float wbs[4608];
    int tid = threadIdx.x;
    for (int i = tid; i < 4096; i += 256) wbs[i + (i >> 6)] = w_blk[i];
    size_t tok = (size_t)blockIdx.x * 4 + (tid >> 6);
    int lane = tid & 63;
    int c0 = lane * 8;
    const float4* p = (const float4*)(x + tok * CC + c0);
    float4 a = p[0], b = p[1];
    uint4 o;
    o.x = (unsigned)f2bf(a.x) | ((unsigned)f2bf(a.y) << 16);
    o.y = (unsigned)f2bf(a.z) | ((unsigned)f2bf(a.w) << 16);
    o.z = (unsigned)f2bf(b.x) | ((unsigned)f2bf(b.y) << 16);
    o.w = (unsigned)f2bf(b.z) | ((unsigned)f2bf(b.w) << 16);
    *(uint4*)(xbf + tok * CC + c0) = o;
    float xv[8] = {a.x, a.y, a.z, a.w, b.x, b.y, b.z, b.w};
    __syncthreads();
    float acc[8];
#pragma unroll
    for (int h = 0; h < 8; ++h) acc[h] = 0.f;
#pragma unroll
    for (int j = 0; j < 8; ++j) {
        const float* wr = &wbs[(c0 + j) * 8 + lane];
#pragma unroll
        for (int h = 0; h < 8; ++h) acc[h] += xv[j] * wr[h];
    }
#pragma unroll
    for (int h = 0; h < 8; ++h) {
#pragma unroll
        for (int off = 1; off < 64; off <<= 1) acc[h] += __shfl_xor(acc[h], off);
    }
    float v = acc[0];
#pragma unroll
    for (int h = 1; h < 8; ++h) v = (lane == h) ? acc[h] : v;
    if (lane < 8) gbl[tok * 8 + lane] = 1.f / (1.f + __expf(-(v + b_blk[lane])));
}

// ---------------- kernel 1: transpose fp32 [K][Nn] -> bf16 [Nn][K] ----------------
__global__ __launch_bounds__(256) void transpose_bf16_kernel(const float* __restrict__ in,
                                                             u16* __restrict__ out,
                                                             int K, int Nn) {
    __shared__ float tile[32][33];
    int n0 = blockIdx.x * 32, k0 = blockIdx.y * 32;
    int tx = threadIdx.x & 31, ty = threadIdx.x >> 5;
#pragma unroll
    for (int i = 0; i < 4; ++i)
        tile[ty + i * 8][tx] = in[(size_t)(k0 + ty + i * 8) * Nn + n0 + tx];
    __syncthreads();
#pragma unroll
    for (int i = 0; i < 4; ++i)
        out[(size_t)(n0 + ty + i * 8) * K + k0 + tx] = f2bf(tile[tx][ty + i * 8]);
}

// ---------------- kernel 2: sbias2/gate2 in MFMA C-fragment layout ----------------
__global__ __launch_bounds__(256) void gate_sbias_kernel(const int* __restrict__ mask,
                                                         const float* __restrict__ edge,
                                                         const float* __restrict__ w1,
                                                         const float* __restrict__ b1,
                                                         const float* __restrict__ w2,
                                                         const float* __restrict__ b2,
                                                         u16* __restrict__ gate2,
                                                         u16* __restrict__ sbias2) {
    __shared__ float w1s[64], b1s[16], w2s[128], b2s[8];
    __shared__ int nds[16];
    int t = threadIdx.x;
    int nb = blockIdx.x >> 2;
    int qt = blockIdx.x & 3;
    if (t < 64) w1s[t] = w1[t];
    if (t < 16) b1s[t] = b1[t];
    if (t < 128) w2s[t] = w2[t];
    if (t < 8) b2s[t] = b2[t];
    if (t >= 128 && t < 144) {
        int q = qt * 16 + (t - 128);
        int s = 0;
        const int* mr = mask + (size_t)(nb * 64 + q) * 64;
#pragma unroll 8
        for (int k = 0; k < 64; ++k) s += mr[k];
        nds[t - 128] = (s < 1) ? 1 : 0;
    }
    __syncthreads();
#pragma unroll 1
    for (int it = 0; it < 4; ++it) {
        int p = it * 256 + t;
        int ql = p >> 6, k = p & 63;
        int q = qt * 16 + ql;
        int pk = (k & 15) * 4 + (k >> 4);
        int mv = mask[(size_t)(nb * 64 + q) * 64 + k];
        float e0, e1, e2, e3;
        if (q == k) {
            mv = max(mv, nds[ql]);
            e0 = e1 = e2 = 0.f;
            e3 = 1.f;
        } else {
            const float* ep = edge + ((size_t)(nb * 64 + q) * 64 + k) * 4;
            e0 = ep[0]; e1 = ep[1]; e2 = ep[2]; e3 = ep[3];
        }
        sbias2[(size_t)(nb * 64 + q) * 64 + pk] = f2bf(mv ? e3 : -1e30f);
        float g[8];
#pragma unroll
        for (int hh = 0; hh < 8; ++hh) g[hh] = b2s[hh];
#pragma unroll
        for (int j = 0; j < 16; ++j) {
            float hpre = e0 * w1s[j] + e1 * w1s[16 + j] + e2 * w1s[32 + j] + e3 * w1s[48 + j] + b1s[j];
            float hg = 0.5f * hpre * (1.f + erff(hpre * 0.70710678f));
#pragma unroll
            for (int hh = 0; hh < 8; ++hh) g[hh] += hg * w2s[j * 8 + hh];
        }
#pragma unroll
        for (int hh = 0; hh < 8; ++hh)
            gate2[(((size_t)nb * 8 + hh) * 64 + q) * 64 + pk] = f2bf(mv ? g[hh] : 0.f);
    }
}

// ---------------- fused qkv-GEMM + attention ----------------
// Block = (b, nb, head-pair), 512 threads (8 waves). Wave w: head hloc = w>>2, n-tile nt = w&3.
// Phase A: per-head-slice QKV GEMM. A = x-block (64x512) staged in LDS per K-step
//   (verified dma16 + XOR-chunk swizzle, 64-row variant, double-buffered).
//   B-fragments loaded directly from global wqkvT (row-major [n][k] => 16B contiguous, L2-hot).
// Phase B: Q/K/V -> LDS in attn layouts, then the verified attention code (4 waves/head).
__global__ __launch_bounds__(512, 4) void fused_qkv_attn_kernel(const u16* __restrict__ xbf,
                                                                const u16* __restrict__ wqkvT,
                                                                const float* __restrict__ b_qkv,
                                                                const u16* __restrict__ sbias2,
                                                                const u16* __restrict__ gate2,
                                                                const float* __restrict__ gbl,
                                                                u16* __restrict__ xmid) {
    __shared__ __align__(16) u16 Xs[2][64 * 64];   // staged x K-tile (chunk-swizzled)
    __shared__ __align__(16) u16 QPs[2][64 * 72];  // Q, overlaid by P after QK^T (same wave+rows)
    __shared__ __align__(16) u16 Ks[2][64 * 72];
    __shared__ __align__(16) u16 VTs[2][64 * 72];
    __shared__ float gl[2][64], vbl[2][64];

    int tid = threadIdx.x;
    int bidf = blockIdx.x;
    int logical = (bidf & 7) * 512 + (bidf >> 3);  // bijective XCD chunk swizzle (4096 % 8 == 0)
    int hp = logical & 3, nb = (logical >> 2) & 511, b = logical >> 11;
    int wave = tid >> 6, lane = tid & 63, l15 = lane & 15, quad = lane >> 4;
    int hloc = wave >> 2;        // 0..1
    int h = hp * 2 + hloc;       // global head
    int nt = wave & 3;           // 16-col slice within head (GEMM) / q-row block (attn)
    int m0 = nt * 16;
    size_t blockrow = (size_t)(b * NTOK + nb * 64);

    // ---- staging addresses (qkv_gemm pattern, 64-row tile across 512 threads) ----
    int srow = tid >> 3;                 // 0..63
    int jch = tid & 7;
    int js = jch ^ (srow & 7);
    const u16* gA = xbf + (blockrow + srow) * CC + js * 8;
    int sw = l15 & 7;

    // ---- B fragment pointers: n = sec*512 + h*64 + nt*16 + l15 ----
    const u16* gB0 = wqkvT + (size_t)(0 * 512 + h * 64 + nt * 16 + l15) * CC;
    const u16* gB1 = wqkvT + (size_t)(1 * 512 + h * 64 + nt * 16 + l15) * CC;
    const u16* gB2 = wqkvT + (size_t)(2 * 512 + h * 64 + nt * 16 + l15) * CC;
    float bq0 = b_qkv[0 * 512 + h * 64 + nt * 16 + l15];
    float bq1 = b_qkv[1 * 512 + h * 64 + nt * 16 + l15];
    float bq2 = b_qkv[2 * 512 + h * 64 + nt * 16 + l15];

    f32x4 accQ[4], accK[4], accV[4];
#pragma unroll
    for (int i = 0; i < 4; ++i) {
        accQ[i] = (f32x4){0.f, 0.f, 0.f, 0.f};
        accK[i] = (f32x4){0.f, 0.f, 0.f, 0.f};
        accV[i] = (f32x4){0.f, 0.f, 0.f, 0.f};
    }

    dma16(gA, &Xs[0][wave * 512]);
    __syncthreads();
    for (int kt = 0; kt < 8; ++kt) {
        int buf = kt & 1;
        if (kt < 7) dma16(gA + (kt + 1) * 64, &Xs[buf ^ 1][wave * 512]);
#pragma unroll
        for (int kk = 0; kk < 2; ++kk) {
            int ch = ((kk * 4 + quad) ^ sw) * 8;
            bf16x8 a[4];
#pragma unroll
            for (int i = 0; i < 4; ++i) a[i] = *(const bf16x8*)&Xs[buf][(i * 16 + l15) * 64 + ch];
            int ko = kt * 64 + kk * 32 + quad * 8;
            bf16x8 b0 = bc8(*(const uint4*)(gB0 + ko));
            bf16x8 b1 = bc8(*(const uint4*)(gB1 + ko));
            bf16x8 b2 = bc8(*(const uint4*)(gB2 + ko));
#pragma unroll
            for (int i = 0; i < 4; ++i) {
                accQ[i] = __builtin_amdgcn_mfma_f32_16x16x32_bf16(a[i], b0, accQ[i], 0, 0, 0);
                accK[i] = __builtin_amdgcn_mfma_f32_16x16x32_bf16(a[i], b1, accK[i], 0, 0, 0);
                accV[i] = __builtin_amdgcn_mfma_f32_16x16x32_bf16(a[i], b2, accV[i], 0, 0, 0);
            }
        }
        __syncthreads();
    }

    // ---- write Q/K/V to LDS in attention layouts ----
    {
        int dloc = nt * 16 + l15;
#pragma unroll
        for (int i = 0; i < 4; ++i) {
#pragma unroll
            for (int r = 0; r < 4; ++r) {
                int tok = i * 16 + quad * 4 + r;
                QPs[hloc][tok * 72 + dloc] = f2bf(accQ[i][r] + bq0);
                Ks[hloc][tok * 72 + dloc] = f2bf(accK[i][r] + bq1);
                VTs[hloc][dloc * 72 + tok] = f2bf(accV[i][r] + bq2);
            }
        }
    }
    if (tid < 128) {
        int hl = tid >> 6, tok = tid & 63;
        gl[hl][tok] = gbl[(blockrow + tok) * 8 + hp * 2 + hl];
    }
    __syncthreads();

    if (tid < 128) {
        int hl = tid >> 6, d = tid & 63;
        float s = 0.f;
#pragma unroll 8
        for (int k = 0; k < 64; ++k) s += bf2f(VTs[hl][d * 72 + k]);
        vbl[hl][d] = s * 0.015625f;
    }

    // ---- QK^T ----
    f32x4 sc[4];
#pragma unroll
    for (int t = 0; t < 4; ++t) sc[t] = (f32x4){0.f, 0.f, 0.f, 0.f};
#pragma unroll
    for (int kk = 0; kk < 2; ++kk) {
        bf16x8 a = *(const bf16x8*)&QPs[hloc][(m0 + l15) * 72 + kk * 32 + quad * 8];
#pragma unroll
        for (int t = 0; t < 4; ++t) {
            bf16x8 bb = *(const bf16x8*)&Ks[hloc][(t * 16 + l15) * 72 + kk * 32 + quad * 8];
            sc[t] = __builtin_amdgcn_mfma_f32_16x16x32_bf16(a, bb, sc[t], 0, 0, 0);
        }
    }
    // ---- softmax + gate, P written over Q's LDS (same wave, same rows) ----
    {
        const u16* sb2 = sbias2 + (size_t)nb * 4096;
        const u16* gp2 = gate2 + ((size_t)nb * 8 + h) * 4096;
#pragma unroll
        for (int r = 0; r < 4; ++r) {
            int q = m0 + quad * 4 + r;
            ushort4 sv = *(const ushort4*)(sb2 + (q * 16 + l15) * 4);
            float bias_t[4] = {bf2f(sv.x), bf2f(sv.y), bf2f(sv.z), bf2f(sv.w)};
            float mx = -3e38f;
#pragma unroll
            for (int t = 0; t < 4; ++t) {
                float v = sc[t][r] * 0.125f + bias_t[t];
                sc[t][r] = v;
                mx = fmaxf(mx, v);
            }
            mx = fmaxf(mx, __shfl_xor(mx, 1));
            mx = fmaxf(mx, __shfl_xor(mx, 2));
            mx = fmaxf(mx, __shfl_xor(mx, 4));
            mx = fmaxf(mx, __shfl_xor(mx, 8));
            float sum = 0.f;
#pragma unroll
            for (int t = 0; t < 4; ++t) {
                float p = __expf(sc[t][r] - mx);
                sc[t][r] = p;
                sum += p;
            }
            sum += __shfl_xor(sum, 1);
            sum += __shfl_xor(sum, 2);
            sum += __shfl_xor(sum, 4);
            sum += __shfl_xor(sum, 8);
            float inv = 1.f / sum;
            ushort4 gv = *(const ushort4*)(gp2 + (q * 16 + l15) * 4);
            float gate_t[4] = {bf2f(gv.x), bf2f(gv.y), bf2f(gv.z), bf2f(gv.w)};
#pragma unroll
            for (int t = 0; t < 4; ++t) {
                float comb = sc[t][r] * inv + gate_t[t];
                QPs[hloc][q * 72 + t * 16 + l15] = f2bf(comb);
            }
        }
    }
    __syncthreads();

    // ---- PV ----
    f32x4 o[4];
#pragma unroll
    for (int t = 0; t < 4; ++t) o[t] = (f32x4){0.f, 0.f, 0.f, 0.f};
#pragma unroll
    for (int kk = 0; kk < 2; ++kk) {
        bf16x8 a = *(const bf16x8*)&QPs[hloc][(m0 + l15) * 72 + kk * 32 + quad * 8];
#pragma unroll
        for (int t = 0; t < 4; ++t) {
            bf16x8 bb = *(const bf16x8*)&VTs[hloc][(t * 16 + l15) * 72 + kk * 32 + quad * 8];
            o[t] = __builtin_amdgcn_mfma_f32_16x16x32_bf16(a, bb, o[t], 0, 0, 0);
        }
    }
#pragma unroll
    for (int t = 0; t < 4; ++t) {
#pragma unroll
        for (int r = 0; r < 4; ++r) {
            int q = m0 + quad * 4 + r, d = t * 16 + l15;
            float v = o[t][r] + gl[hloc][q] * vbl[hloc][d];
            xmid[(blockrow + q) * CC + h * 64 + d] = f2bf(v);
        }
    }
}

// ---------------- out = x_mid @ w_proj + b_proj (fp32 out) ----------------
__global__ __launch_bounds__(256) void outproj_kernel(const u16* __restrict__ xmid,
                                                      const u16* __restrict__ wprojT,
                                                      const float* __restrict__ b_proj,
                                                      float* __restrict__ out) {
    __shared__ __align__(16) u16 As[128 * 64], Bs[128 * 64];
    int tid = threadIdx.x;
    int flat = blockIdx.x;                     // 2048 blocks
    int logical = (flat & 7) * 256 + (flat >> 3);
    int n0 = (logical & 3) * 128;
    int m0 = (logical >> 2) * 128;
    int lane = tid & 63, l15 = lane & 15, quad = lane >> 4, wave = tid >> 6;
    int r8 = lane >> 3, jch = lane & 7;
    int js = jch ^ r8;
    int mwl = (wave >> 1) * 64, nwl = (wave & 1) * 64;
    int sw = l15 & 7;

    f32x4 acc[4][4];
#pragma unroll
    for (int i = 0; i < 4; ++i)
#pragma unroll
        for (int j = 0; j < 4; ++j) acc[i][j] = (f32x4){0.f, 0.f, 0.f, 0.f};

    int arow[4], brow[4];
#pragma unroll
    for (int i = 0; i < 4; ++i) arow[i] = (mwl + i * 16 + l15) * 64;
#pragma unroll
    for (int j = 0; j < 4; ++j) brow[j] = (nwl + j * 16 + l15) * 64;

    const u16* gA = xmid + (size_t)(m0 + wave * 32 + r8) * CC + js * 8;
    const u16* gB = wprojT + (size_t)(n0 + wave * 32 + r8) * CC + js * 8;
    u16* lA = As + wave * 32 * 64;
    u16* lB = Bs + wave * 32 * 64;

    for (int kt = 0; kt < 8; ++kt) {
        int k0 = kt * 64;
#pragma unroll
        for (int t = 0; t < 4; ++t) {
            dma16(gA + (size_t)t * 8 * CC + k0, lA + t * 8 * 64);
            dma16(gB + (size_t)t * 8 * CC + k0, lB + t * 8 * 64);
        }
        __syncthreads();
#pragma unroll
        for (int kk = 0; kk < 2; ++kk) {
            int ch = ((kk * 4 + quad) ^ sw) * 8;
            bf16x8 a[4], bb[4];
#pragma unroll
            for (int i = 0; i < 4; ++i) a[i] = *(const bf16x8*)&As[arow[i] + ch];
#pragma unroll
            for (int j = 0; j < 4; ++j) bb[j] = *(const bf16x8*)&Bs[brow[j] + ch];
#pragma unroll
            for (int i = 0; i < 4; ++i)
#pragma unroll
                for (int j = 0; j < 4; ++j)
                    acc[i][j] = __builtin_amdgcn_mfma_f32_16x16x32_bf16(a[i], bb[j], acc[i][j], 0, 0, 0);
        }
        __syncthreads();
    }
#pragma unroll
    for (int i = 0; i < 4; ++i)
#pragma unroll
        for (int j = 0; j < 4; ++j) {
            int col = n0 + nwl + j * 16 + l15;
            float bp = b_proj[col];
#pragma unroll
            for (int r = 0; r < 4; ++r) {
                int row = m0 + mwl + i * 16 + quad * 4 + r;
                out[(size_t)row * CC + col] = acc[i][j][r] + bp;
            }
        }
}

extern "C" void kernel_launch(void* const* d_in, const int* in_sizes, int n_in,
                              void* d_out, int out_size, void* d_ws, size_t ws_size,
                              hipStream_t stream) {
    const float* x = (const float*)d_in[0];
    const int* attn_mask = (const int*)d_in[1];
    const float* edge = (const float*)d_in[2];
    const float* w_qkv = (const float*)d_in[3];
    const float* b_qkv = (const float*)d_in[4];
    const float* w_proj = (const float*)d_in[5];
    const float* b_proj = (const float*)d_in[6];
    const float* w_eg1 = (const float*)d_in[7];
    const float* b_eg1 = (const float*)d_in[8];
    const float* w_eg2 = (const float*)d_in[9];
    const float* b_eg2 = (const float*)d_in[10];
    const float* w_blk = (const float*)d_in[11];
    const float* b_blk = (const float*)d_in[12];
    float* out = (float*)d_out;

    char* ws = (char*)d_ws;
    u16* xbf = (u16*)ws;                            // 67108864 bytes
    u16* xmid = (u16*)(ws + 67108864);              // 67108864 (was qkv region; xbf is read
                                                    // by fused kernel, so no aliasing)
    u16* gate2 = (u16*)(ws + 268435456);            // 33554432
    u16* sbias2 = (u16*)(ws + 301989888);           // 4194304
    u16* wqkvT = (u16*)(ws + 306184192);            // 1572864
    u16* wprojT = (u16*)(ws + 307757056);           // 524288
    float* gbl = (float*)(ws + 308281344);          // 2097152

    convert_gblock_kernel<<<16384, 256, 0, stream>>>(x, xbf, w_blk, b_blk, gbl);
    transpose_bf16_kernel<<<dim3(48, 16), 256, 0, stream>>>(w_qkv, wqkvT, 512, 1536);
    transpose_bf16_kernel<<<dim3(16, 16), 256, 0, stream>>>(w_proj, wprojT, 512, 512);
    gate_sbias_kernel<<<2048, 256, 0, stream>>>(attn_mask, edge, w_eg1, b_eg1, w_eg2, b_eg2,
                                                gate2, sbias2);
    fused_qkv_attn_kernel<<<4096, 512, 0, stream>>>(xbf, wqkvT, b_qkv, sbias2, gate2, gbl, xmid);
    outproj_kernel<<<2048, 256, 0, stream>>>(xmid, wprojT, b_proj, out);
}